// Round 7
// baseline (109.759 us; speedup 1.0000x reference)
//
#include <hip/hip_runtime.h>
#include <math.h>

#define B_  8
#define NV_ 128
#define NQ_ 512
#define KD_ 128
#define P_  512
#define H_  2
#define D_  256

typedef unsigned short ushort_t;
typedef unsigned int   uint_t;
typedef __attribute__((ext_vector_type(8))) short bf16x8;
typedef __attribute__((ext_vector_type(4))) float f32x4;

// workspace layout (byte offsets)
#define QBF_OFF  0                     // bf16 [b][h][j][d]  4 MB
#define VWA_OFF  (4u<<20)              // bf16 [b][h][i][d]  1 MB (v * wa)
#define VT_OFF   (5u<<20)              // bf16 [b][h][d][i]  1 MB
#define HEAD_OFF (7u<<20)              // f32  [b][h][d]     16 KB
#define WVT_OFF  (8u<<20)              // bf16 WvT [512][128] 128 KB
#define WQT_OFF  ((8u<<20) + (128u<<10)) // bf16 WqT [512][128] 128 KB

__device__ __forceinline__ ushort_t f2b(float f) {
    uint_t u = __float_as_uint(f);
    uint_t r = (u + 0x7FFFu + ((u >> 16) & 1u)) >> 16;   // RNE
    return (ushort_t)r;
}
__device__ __forceinline__ float b2f(ushort_t u) {
    return __uint_as_float(((uint_t)u) << 16);
}

// ---------------------------------------------------------------------------
// K0 prep: WT[c][k] = bf16(W[k][c]) for Wv,Wq; zero head accumulator.
// grid = 8 blocks: bid>>2 selects W, bid&3 selects 128-col chunk.
// ---------------------------------------------------------------------------
extern "C" __global__ void __launch_bounds__(256) prep_kernel(
    const float* __restrict__ Wv, const float* __restrict__ Wq,
    char* __restrict__ ws)
{
    ushort_t* wvt = (ushort_t*)(ws + WVT_OFF);
    ushort_t* wqt = (ushort_t*)(ws + WQT_OFF);
    float*    head = (float*)(ws + HEAD_OFF);

    __shared__ ushort_t lt[128][132];   // [k][c], stride 132 elems (264 B)

    const int bid = blockIdx.x, t = threadIdx.x;
    const int wsel = bid >> 2, cc = bid & 3, c0 = cc * 128;
    const float* W = wsel ? Wq : Wv;
    ushort_t*   WT = wsel ? wqt : wvt;

    head[bid * 512 + t] = 0.f;
    head[bid * 512 + t + 256] = 0.f;

    // load 128k x 128c chunk, convert to bf16 into LDS
    for (int it = 0; it < 16; ++it) {
        const int idx = it * 256 + t;
        const int k = idx >> 5, cq = (idx & 31) * 4;
        const float4 f = *(const float4*)&W[(size_t)k * P_ + c0 + cq];
        uint_t* dst = (uint_t*)&lt[k][cq];
        dst[0] = (uint_t)f2b(f.x) | ((uint_t)f2b(f.y) << 16);
        dst[1] = (uint_t)f2b(f.z) | ((uint_t)f2b(f.w) << 16);
    }
    __syncthreads();

    // write WT[c][k] rows, packed 16B
    for (int it = 0; it < 8; ++it) {
        const int idx = it * 256 + t;
        const int c = idx & 127, kg = idx >> 7;   // kg 0..15
        bf16x8 u;
#pragma unroll
        for (int r = 0; r < 8; ++r) u[r] = (short)lt[kg * 8 + r][c];
        *(bf16x8*)&WT[(size_t)(c0 + c) * 128 + kg * 8] = u;
    }
}

// ---------------------------------------------------------------------------
// K1 proj (MFMA): X(64xK128) @ W(128x512) per block. 80 blocks:
// bid<16 -> v-tiles, else q-tiles. 4 waves, wave w -> cols [128w,128w+128).
// Epilogue via LDS, two 256-col passes; v-blocks also emit vT (fused
// transpose).  (verified round 6)
// ---------------------------------------------------------------------------
extern "C" __global__ void __launch_bounds__(256, 1) proj_kernel(
    const float* __restrict__ v, const float* __restrict__ q,
    const float* __restrict__ bv, const float* __restrict__ bq,
    const float* __restrict__ wa, char* __restrict__ ws)
{
    ushort_t* qbf = (ushort_t*)(ws + QBF_OFF);
    ushort_t* vwa = (ushort_t*)(ws + VWA_OFF);
    ushort_t* vT  = (ushort_t*)(ws + VT_OFF);

    __shared__ __align__(16) char ldsb[64 * 264 * 2];   // 33792 B union
    ushort_t (*A)[136] = (ushort_t (*)[136])ldsb;       // staging, 17408 B
    ushort_t (*O)[264] = (ushort_t (*)[264])ldsb;       // epilogue tile

    const int bid = blockIdx.x, t = threadIdx.x;
    const int w = t >> 6, l = t & 63, l15 = l & 15, lg = l >> 4;

    const bool is_v = (bid < 16);
    int b, r0;
    const float* src; const float* bias;
    if (is_v) { const int tv = bid;      b = tv >> 1; r0 = (tv & 1) * 64; src = v + (size_t)(b * NV_ + r0) * KD_; bias = bv; }
    else      { const int tq = bid - 16; b = tq >> 3; r0 = (tq & 7) * 64; src = q + (size_t)(b * NQ_ + r0) * KD_; bias = bq; }
    const ushort_t* WT = (const ushort_t*)(ws + (is_v ? WVT_OFF : WQT_OFF));

    // ---- stage A: 64 rows x 128 k, f32 -> bf16 LDS ----
    for (int it = 0; it < 8; ++it) {
        const int idx = it * 256 + t;
        const int row = idx >> 5, kq = (idx & 31) * 4;
        const float4 f = *(const float4*)&src[(size_t)row * KD_ + kq];
        uint_t* dst = (uint_t*)&A[row][kq];
        dst[0] = (uint_t)f2b(f.x) | ((uint_t)f2b(f.y) << 16);
        dst[1] = (uint_t)f2b(f.z) | ((uint_t)f2b(f.w) << 16);
    }
    __syncthreads();

    // ---- MFMA: wave w computes 64 x 128 at n0 = 128w ----
    const int n0 = w * 128;
    f32x4 acc[4][8];
#pragma unroll
    for (int mf = 0; mf < 4; ++mf)
#pragma unroll
        for (int nf = 0; nf < 8; ++nf) acc[mf][nf] = (f32x4){0.f, 0.f, 0.f, 0.f};

#pragma unroll
    for (int ks = 0; ks < 4; ++ks) {
        const int ko = ks * 32 + lg * 8;
        bf16x8 Af[4];
#pragma unroll
        for (int mf = 0; mf < 4; ++mf)
            Af[mf] = *(const bf16x8*)&A[mf * 16 + l15][ko];
        bf16x8 Bf[8];
#pragma unroll
        for (int nf = 0; nf < 8; ++nf)
            Bf[nf] = *(const bf16x8*)&WT[(size_t)(n0 + nf * 16 + l15) * 128 + ko];
#pragma unroll
        for (int mf = 0; mf < 4; ++mf)
#pragma unroll
            for (int nf = 0; nf < 8; ++nf)
                acc[mf][nf] = __builtin_amdgcn_mfma_f32_16x16x32_bf16(Af[mf], Bf[nf], acc[mf][nf], 0, 0, 0);
    }
    __syncthreads();   // A-LDS dead; O may now be written

    // ---- epilogue: two passes over col halves (head p) ----
    for (int p = 0; p < 2; ++p) {
        if ((w >> 1) == p) {
            const int nbase = (w & 1) * 128;
#pragma unroll
            for (int mf = 0; mf < 4; ++mf)
#pragma unroll
                for (int nf = 0; nf < 8; ++nf) {
                    const int m = mf * 16 + lg * 4;
                    const int n = nbase + nf * 16 + l15;
                    const float bcol = bias[p * 256 + n];   // col bias
#pragma unroll
                    for (int r = 0; r < 4; ++r)
                        O[m + r][n] = f2b(acc[mf][nf][r] + bcol);
                }
        }
        __syncthreads();
        // stream out 64 x 256 half, coalesced bf16x8
        for (int it = 0; it < 8; ++it) {
            const int idx = it * 256 + t;
            const int row = idx >> 5, d0 = (idx & 31) * 8;
            const bf16x8 u = *(const bf16x8*)&O[row][d0];
            if (is_v) {
                const float4 wa0 = *(const float4*)&wa[d0];
                const float4 wa1 = *(const float4*)&wa[d0 + 4];
                bf16x8 s;
                s[0] = (short)f2b(b2f((ushort_t)u[0]) * wa0.x);
                s[1] = (short)f2b(b2f((ushort_t)u[1]) * wa0.y);
                s[2] = (short)f2b(b2f((ushort_t)u[2]) * wa0.z);
                s[3] = (short)f2b(b2f((ushort_t)u[3]) * wa0.w);
                s[4] = (short)f2b(b2f((ushort_t)u[4]) * wa1.x);
                s[5] = (short)f2b(b2f((ushort_t)u[5]) * wa1.y);
                s[6] = (short)f2b(b2f((ushort_t)u[6]) * wa1.z);
                s[7] = (short)f2b(b2f((ushort_t)u[7]) * wa1.w);
                *(bf16x8*)&vwa[((size_t)(b * 2 + p) * 128 + r0 + row) * 256 + d0] = s;
            } else {
                *(bf16x8*)&qbf[((size_t)(b * 2 + p) * 512 + r0 + row) * 256 + d0] = u;
            }
        }
        if (is_v) {
            // fused transpose: vT[bh][d][i], i = r0 + ic*8 + r, from O[i_loc][d]
            for (int it = 0; it < 8; ++it) {
                const int d  = (t & 63) + (it & 3) * 64;
                const int ic = (t >> 6) + (it >> 2) * 4;
                bf16x8 u;
#pragma unroll
                for (int r = 0; r < 8; ++r) u[r] = (short)O[ic * 8 + r][d];
                *(bf16x8*)&vT[((size_t)(b * 2 + p) * 256 + d) * 128 + r0 + ic * 8] = u;
            }
        }
        __syncthreads();
    }
}

// ---------------------------------------------------------------------------
// K2 att: per (b,h,j-tile 16): MFMA score -> column softmax -> att write ->
//     MFMA W = P^T V -> head partial via atomics.
// grid = 8*2*32 = 512 blocks (2 blocks/CU -> 2 waves/SIMD), 256 threads.
// Score B-fragments read directly from L2-resident qbf (identical values to
// the old q_lds path); q_lds is only consumed in the head contraction, so
// its staging drains under the score MFMAs.
// ---------------------------------------------------------------------------
extern "C" __global__ void __launch_bounds__(256) att_kernel(
    char* __restrict__ ws, float* __restrict__ out)
{
    const ushort_t* qbf = (const ushort_t*)(ws + QBF_OFF);
    const ushort_t* vwa = (const ushort_t*)(ws + VWA_OFF);
    const ushort_t* vT  = (const ushort_t*)(ws + VT_OFF);
    float*          head = (float*)(ws + HEAD_OFF);
    float*          att_out = out + B_ * D_;

    __shared__ ushort_t q_lds[16][264];   // +8 pad: 2-way banks
    __shared__ ushort_t p_lds[16][136];   // [j][i]
    __shared__ float wmax[4][16];
    __shared__ float wsum[4][16];

    const int t  = threadIdx.x;
    const int w  = t >> 6;
    const int l  = t & 63;
    const int l15 = l & 15, lg = l >> 4;

    const int bid = blockIdx.x;
    const int jt  = bid & 31;
    const int h   = (bid >> 5) & 1;
    const int b   = bid >> 6;
    const int j0  = jt * 16;
    const size_t bh = (size_t)(b * H_ + h);

    const ushort_t* vwa_p = vwa + bh * 128 * 256;
    const ushort_t* vT_p  = vT  + bh * 256 * 128;
    const ushort_t* qp    = qbf + (bh * 512 + j0) * 256;

    // ---- issue Q tile stage (16 x 256 bf16); consumed only in head phase ----
    for (int c = t; c < 512; c += 256) {
        const int row = c >> 5, c8 = (c & 31) * 8;
        *(bf16x8*)&q_lds[row][c8] = *(const bf16x8*)&qp[(size_t)row * 256 + c8];
    }

    // ---- score: S[i,j] = sum_d vwa[i,d] q[j,d]; wave w -> i in [32w,32w+32) ----
    const ushort_t* a0  = vwa_p + (size_t)(w * 32 + l15) * 256 + lg * 8;
    const ushort_t* a1  = a0 + 16 * 256;
    const ushort_t* bqg = qp + (size_t)l15 * 256 + lg * 8;   // global B-frag base

    f32x4 acc0 = (f32x4){0.f, 0.f, 0.f, 0.f};
    f32x4 acc1 = acc0;

    __builtin_amdgcn_s_setprio(1);
#pragma unroll
    for (int ks = 0; ks < 8; ++ks) {
        const int ko = ks * 32;
        const bf16x8 A0 = *(const bf16x8*)(a0 + ko);
        const bf16x8 A1 = *(const bf16x8*)(a1 + ko);
        const bf16x8 B0 = *(const bf16x8*)(bqg + ko);
        acc0 = __builtin_amdgcn_mfma_f32_16x16x32_bf16(A0, B0, acc0, 0, 0, 0);
        acc1 = __builtin_amdgcn_mfma_f32_16x16x32_bf16(A1, B0, acc1, 0, 0, 0);
    }
    __builtin_amdgcn_s_setprio(0);
    // lane's acc{0,1}[r]: i = w*32 + {0,16} + lg*4 + r ; j = j0 + l15

    // ---- column (over i) softmax ----
    float mx = acc0[0];
#pragma unroll
    for (int r = 0; r < 4; ++r) { mx = fmaxf(mx, acc0[r]); mx = fmaxf(mx, acc1[r]); }
    mx = fmaxf(mx, __shfl_xor(mx, 16));
    mx = fmaxf(mx, __shfl_xor(mx, 32));
    if (l < 16) wmax[w][l] = mx;
    __syncthreads();   // also covers q_lds staging

    const float cm = fmaxf(fmaxf(wmax[0][l15], wmax[1][l15]),
                           fmaxf(wmax[2][l15], wmax[3][l15]));

    float sm = 0.f;
#pragma unroll
    for (int r = 0; r < 4; ++r) {
        const float e0 = __expf(acc0[r] - cm);
        const float e1 = __expf(acc1[r] - cm);
        acc0[r] = e0; acc1[r] = e1;
        sm += e0 + e1;
    }
    sm += __shfl_xor(sm, 16);
    sm += __shfl_xor(sm, 32);
    if (l < 16) wsum[w][l] = sm;
    __syncthreads();

    const float cinv = 1.f / (wsum[0][l15] + wsum[1][l15] + wsum[2][l15] + wsum[3][l15]);

    // ---- scale, write att (f32), pack p to LDS [j][i] bf16 ----
    float* attp = att_out + (bh * 128) * 512 + j0;
    const int jl = l15;
#pragma unroll
    for (int mb = 0; mb < 2; ++mb) {
        const int il = w * 32 + mb * 16 + lg * 4;
        const f32x4 a = mb ? acc1 : acc0;
        const float p0 = a[0] * cinv, p1 = a[1] * cinv;
        const float p2 = a[2] * cinv, p3 = a[3] * cinv;
        attp[(size_t)(il + 0) * 512 + jl] = p0;
        attp[(size_t)(il + 1) * 512 + jl] = p1;
        attp[(size_t)(il + 2) * 512 + jl] = p2;
        attp[(size_t)(il + 3) * 512 + jl] = p3;
        const uint_t u01 = (uint_t)f2b(p0) | ((uint_t)f2b(p1) << 16);
        const uint_t u23 = (uint_t)f2b(p2) | ((uint_t)f2b(p3) << 16);
        *(uint_t*)&p_lds[jl][il + 0] = u01;
        *(uint_t*)&p_lds[jl][il + 2] = u23;
    }
    __syncthreads();

    // ---- W = P^T V : W[j,d] = sum_i p[j,i] vT[d,i]; wave w -> d in [64w,64w+64) ----
    f32x4 wacc[4];
#pragma unroll
    for (int nb = 0; nb < 4; ++nb) wacc[nb] = (f32x4){0.f, 0.f, 0.f, 0.f};

    const ushort_t* pb0 = &p_lds[l15][lg * 8];
    const ushort_t* vb0 = vT_p + (size_t)(w * 64 +  0 + l15) * 128 + lg * 8;
    const ushort_t* vb1 = vT_p + (size_t)(w * 64 + 16 + l15) * 128 + lg * 8;
    const ushort_t* vb2 = vT_p + (size_t)(w * 64 + 32 + l15) * 128 + lg * 8;
    const ushort_t* vb3 = vT_p + (size_t)(w * 64 + 48 + l15) * 128 + lg * 8;

    __builtin_amdgcn_s_setprio(1);
#pragma unroll
    for (int ks = 0; ks < 4; ++ks) {
        const int ko = ks * 32;
        const bf16x8 PA0 = *(const bf16x8*)(pb0 + ko);
        const bf16x8 VB0 = *(const bf16x8*)(vb0 + ko);
        const bf16x8 VB1 = *(const bf16x8*)(vb1 + ko);
        const bf16x8 VB2 = *(const bf16x8*)(vb2 + ko);
        const bf16x8 VB3 = *(const bf16x8*)(vb3 + ko);
        wacc[0] = __builtin_amdgcn_mfma_f32_16x16x32_bf16(PA0, VB0, wacc[0], 0, 0, 0);
        wacc[1] = __builtin_amdgcn_mfma_f32_16x16x32_bf16(PA0, VB1, wacc[1], 0, 0, 0);
        wacc[2] = __builtin_amdgcn_mfma_f32_16x16x32_bf16(PA0, VB2, wacc[2], 0, 0, 0);
        wacc[3] = __builtin_amdgcn_mfma_f32_16x16x32_bf16(PA0, VB3, wacc[3], 0, 0, 0);
    }
    __builtin_amdgcn_s_setprio(0);
    // wacc[nb][r]: j_loc = lg*4 + r ; d = w*64 + nb*16 + l15

    // ---- head partial: hd[d] = sum_{j in tile} q[j,d] * W[j,d] ----
    float hd[4] = {0.f, 0.f, 0.f, 0.f};
#pragma unroll
    for (int nb = 0; nb < 4; ++nb) {
        const int d = w * 64 + nb * 16 + l15;
#pragma unroll
        for (int r = 0; r < 4; ++r) {
            const int jq = lg * 4 + r;
            hd[nb] = fmaf(wacc[nb][r], b2f(q_lds[jq][d]), hd[nb]);
        }
        hd[nb] += __shfl_xor(hd[nb], 16);
        hd[nb] += __shfl_xor(hd[nb], 32);
    }
    if (l < 16) {
        float* hp = head + bh * 256 + w * 64 + l;
        atomicAdd(hp +  0, hd[0]);
        atomicAdd(hp + 16, hd[1]);
        atomicAdd(hp + 32, hd[2]);
        atomicAdd(hp + 48, hd[3]);
    }
}

// ---------------------------------------------------------------------------
// K3 out: fused = head.reshape(8,512) @ Wo + bo.  32 blocks.
// ---------------------------------------------------------------------------
extern "C" __global__ void __launch_bounds__(256) out_kernel(
    const float* __restrict__ Wo, const float* __restrict__ bo,
    const char* __restrict__ ws, float* __restrict__ out)
{
    const float* head = (const float*)(ws + HEAD_OFF);
    __shared__ __align__(16) float hs[512];
    __shared__ float ored[4][64];

    const int bid = blockIdx.x, t = threadIdx.x;
    const int b = bid >> 2, cg = bid & 3;
    const int col = cg * 64 + (t & 63), kq = t >> 6;

    hs[t]       = head[(size_t)b * 512 + t];
    hs[t + 256] = head[(size_t)b * 512 + t + 256];
    __syncthreads();

    float acc = 0.f;
    const int kbeg = kq * 128;
    for (int k = kbeg; k < kbeg + 128; k += 4) {
        const float4 hk = *(const float4*)&hs[k];
        acc = fmaf(hk.x, Wo[(size_t)(k+0)*256 + col], acc);
        acc = fmaf(hk.y, Wo[(size_t)(k+1)*256 + col], acc);
        acc = fmaf(hk.z, Wo[(size_t)(k+2)*256 + col], acc);
        acc = fmaf(hk.w, Wo[(size_t)(k+3)*256 + col], acc);
    }
    ored[kq][t & 63] = acc;
    __syncthreads();
    if (t < 64) {
        const float r = ored[0][t] + ored[1][t] + ored[2][t] + ored[3][t] + bo[col];
        out[(size_t)b * 256 + col] = r;
    }
}

// ---------------------------------------------------------------------------
extern "C" void kernel_launch(void* const* d_in, const int* in_sizes, int n_in,
                              void* d_out, int out_size, void* d_ws, size_t ws_size,
                              hipStream_t stream)
{
    const float* v  = (const float*)d_in[0];
    const float* q  = (const float*)d_in[1];
    const float* Wv = (const float*)d_in[2];
    const float* bv = (const float*)d_in[3];
    const float* Wq = (const float*)d_in[4];
    const float* bq = (const float*)d_in[5];
    const float* wa = (const float*)d_in[6];
    // d_in[7] = ba: uniform shift within each softmax column -> no effect on outputs
    const float* Wo = (const float*)d_in[8];
    const float* bo = (const float*)d_in[9];
    float* out = (float*)d_out;
    char*  ws  = (char*)d_ws;

    hipLaunchKernelGGL(prep_kernel, dim3(8),   dim3(256), 0, stream, Wv, Wq, ws);
    hipLaunchKernelGGL(proj_kernel, dim3(80),  dim3(256), 0, stream, v, q, bv, bq, wa, ws);
    hipLaunchKernelGGL(att_kernel,  dim3(512), dim3(256), 0, stream, ws, out);
    hipLaunchKernelGGL(out_kernel,  dim3(32),  dim3(256), 0, stream, Wo, bo, ws, out);
}

// Round 8
// 100.857 us; speedup vs baseline: 1.0883x; 1.0883x over previous
//
#include <hip/hip_runtime.h>
#include <math.h>

#define B_  8
#define NV_ 128
#define NQ_ 512
#define KD_ 128
#define P_  512
#define H_  2
#define D_  256

typedef unsigned short ushort_t;
typedef unsigned int   uint_t;
typedef __attribute__((ext_vector_type(8))) short bf16x8;
typedef __attribute__((ext_vector_type(4))) float f32x4;

// workspace layout (byte offsets)
#define QBF_OFF  0                     // bf16 [b][h][j][d]  4 MB
#define VWA_OFF  (4u<<20)              // bf16 [b][h][i][d]  1 MB (v * wa)
#define VT_OFF   (5u<<20)              // bf16 [b][h][d][i]  1 MB
#define HEAD_OFF (7u<<20)              // f32  [b][h][d]     16 KB
#define WVT_OFF  (8u<<20)              // bf16 WvT [512][128] 128 KB
#define WQT_OFF  ((8u<<20) + (128u<<10)) // bf16 WqT [512][128] 128 KB

__device__ __forceinline__ ushort_t f2b(float f) {
    uint_t u = __float_as_uint(f);
    uint_t r = (u + 0x7FFFu + ((u >> 16) & 1u)) >> 16;   // RNE
    return (ushort_t)r;
}
__device__ __forceinline__ float b2f(ushort_t u) {
    return __uint_as_float(((uint_t)u) << 16);
}

// ---------------------------------------------------------------------------
// K0 prep: WT[c][k] = bf16(W[k][c]) for Wv,Wq; zero head accumulator.
// grid = 32 blocks (was 8): bid>>4 selects W, bid&15 selects 32-col chunk.
// 4x the CUs on the HBM-latency-bound W read.
// ---------------------------------------------------------------------------
extern "C" __global__ void __launch_bounds__(256) prep_kernel(
    const float* __restrict__ Wv, const float* __restrict__ Wq,
    char* __restrict__ ws)
{
    ushort_t* wvt = (ushort_t*)(ws + WVT_OFF);
    ushort_t* wqt = (ushort_t*)(ws + WQT_OFF);
    float*    head = (float*)(ws + HEAD_OFF);

    __shared__ ushort_t lt[128][34];   // [k][c], stride 34 elems (68 B, odd dwords)

    const int bid = blockIdx.x, t = threadIdx.x;
    const int wsel = bid >> 4, cb = bid & 15, c0 = cb * 32;
    const float* W = wsel ? Wq : Wv;
    ushort_t*   WT = wsel ? wqt : wvt;

    if (t < 128) head[bid * 128 + t] = 0.f;   // 32 blocks x 128 = 4096 floats

    // load 128k x 32c chunk, convert to bf16 into LDS
#pragma unroll
    for (int it = 0; it < 4; ++it) {
        const int idx = it * 256 + t;
        const int k = idx >> 3, cq = (idx & 7) * 4;
        const float4 f = *(const float4*)&W[(size_t)k * P_ + c0 + cq];
        uint_t* dst = (uint_t*)&lt[k][cq];
        dst[0] = (uint_t)f2b(f.x) | ((uint_t)f2b(f.y) << 16);
        dst[1] = (uint_t)f2b(f.z) | ((uint_t)f2b(f.w) << 16);
    }
    __syncthreads();

    // write WT[c][k] rows, packed 16B
#pragma unroll
    for (int it = 0; it < 2; ++it) {
        const int idx = it * 256 + t;
        const int c = idx & 31, kg = idx >> 5;   // kg 0..15
        bf16x8 u;
#pragma unroll
        for (int r = 0; r < 8; ++r) u[r] = (short)lt[kg * 8 + r][c];
        *(bf16x8*)&WT[(size_t)(c0 + c) * 128 + kg * 8] = u;
    }
}

// ---------------------------------------------------------------------------
// K1 proj (MFMA): X(32xK128) @ W(128x512) per block. 160 blocks (was 80,
// M-tile halved 64->32 for 2x CU coverage): bid<32 -> v-tiles, else q-tiles.
// 4 waves, wave w -> cols [128w,128w+128). Epilogue via LDS, two 256-col
// passes; v-blocks also emit vT (fused transpose).
// ---------------------------------------------------------------------------
extern "C" __global__ void __launch_bounds__(256) proj_kernel(
    const float* __restrict__ v, const float* __restrict__ q,
    const float* __restrict__ bv, const float* __restrict__ bq,
    const float* __restrict__ wa, char* __restrict__ ws)
{
    ushort_t* qbf = (ushort_t*)(ws + QBF_OFF);
    ushort_t* vwa = (ushort_t*)(ws + VWA_OFF);
    ushort_t* vT  = (ushort_t*)(ws + VT_OFF);

    __shared__ __align__(16) char ldsb[32 * 264 * 2];   // 16896 B union
    ushort_t (*A)[136] = (ushort_t (*)[136])ldsb;       // staging, 8704 B
    ushort_t (*O)[264] = (ushort_t (*)[264])ldsb;       // epilogue tile

    const int bid = blockIdx.x, t = threadIdx.x;
    const int w = t >> 6, l = t & 63, l15 = l & 15, lg = l >> 4;

    const bool is_v = (bid < 32);
    int b, r0;
    const float* src; const float* bias;
    if (is_v) { b = bid >> 2;                r0 = (bid & 3) * 32;  src = v + (size_t)(b * NV_ + r0) * KD_; bias = bv; }
    else      { const int tq = bid - 32; b = tq >> 4; r0 = (tq & 15) * 32; src = q + (size_t)(b * NQ_ + r0) * KD_; bias = bq; }
    const ushort_t* WT = (const ushort_t*)(ws + (is_v ? WVT_OFF : WQT_OFF));

    // ---- stage A: 32 rows x 128 k, f32 -> bf16 LDS ----
#pragma unroll
    for (int it = 0; it < 4; ++it) {
        const int idx = it * 256 + t;
        const int row = idx >> 5, kq = (idx & 31) * 4;
        const float4 f = *(const float4*)&src[(size_t)row * KD_ + kq];
        uint_t* dst = (uint_t*)&A[row][kq];
        dst[0] = (uint_t)f2b(f.x) | ((uint_t)f2b(f.y) << 16);
        dst[1] = (uint_t)f2b(f.z) | ((uint_t)f2b(f.w) << 16);
    }
    __syncthreads();

    // ---- MFMA: wave w computes 32 x 128 at n0 = 128w ----
    const int n0 = w * 128;
    f32x4 acc[2][8];
#pragma unroll
    for (int mf = 0; mf < 2; ++mf)
#pragma unroll
        for (int nf = 0; nf < 8; ++nf) acc[mf][nf] = (f32x4){0.f, 0.f, 0.f, 0.f};

#pragma unroll
    for (int ks = 0; ks < 4; ++ks) {
        const int ko = ks * 32 + lg * 8;
        bf16x8 Af[2];
#pragma unroll
        for (int mf = 0; mf < 2; ++mf)
            Af[mf] = *(const bf16x8*)&A[mf * 16 + l15][ko];
        bf16x8 Bf[8];
#pragma unroll
        for (int nf = 0; nf < 8; ++nf)
            Bf[nf] = *(const bf16x8*)&WT[(size_t)(n0 + nf * 16 + l15) * 128 + ko];
#pragma unroll
        for (int mf = 0; mf < 2; ++mf)
#pragma unroll
            for (int nf = 0; nf < 8; ++nf)
                acc[mf][nf] = __builtin_amdgcn_mfma_f32_16x16x32_bf16(Af[mf], Bf[nf], acc[mf][nf], 0, 0, 0);
    }
    __syncthreads();   // A-LDS dead; O may now be written

    // ---- epilogue: two passes over col halves (head p) ----
    for (int p = 0; p < 2; ++p) {
        if ((w >> 1) == p) {
            const int nbase = (w & 1) * 128;
#pragma unroll
            for (int mf = 0; mf < 2; ++mf)
#pragma unroll
                for (int nf = 0; nf < 8; ++nf) {
                    const int m = mf * 16 + lg * 4;
                    const int n = nbase + nf * 16 + l15;
                    const float bcol = bias[p * 256 + n];   // col bias
#pragma unroll
                    for (int r = 0; r < 4; ++r)
                        O[m + r][n] = f2b(acc[mf][nf][r] + bcol);
                }
        }
        __syncthreads();
        // stream out 32 x 256 half, coalesced bf16x8
#pragma unroll
        for (int it = 0; it < 4; ++it) {
            const int idx = it * 256 + t;
            const int row = idx >> 5, d0 = (idx & 31) * 8;
            const bf16x8 u = *(const bf16x8*)&O[row][d0];
            if (is_v) {
                const float4 wa0 = *(const float4*)&wa[d0];
                const float4 wa1 = *(const float4*)&wa[d0 + 4];
                bf16x8 s;
                s[0] = (short)f2b(b2f((ushort_t)u[0]) * wa0.x);
                s[1] = (short)f2b(b2f((ushort_t)u[1]) * wa0.y);
                s[2] = (short)f2b(b2f((ushort_t)u[2]) * wa0.z);
                s[3] = (short)f2b(b2f((ushort_t)u[3]) * wa0.w);
                s[4] = (short)f2b(b2f((ushort_t)u[4]) * wa1.x);
                s[5] = (short)f2b(b2f((ushort_t)u[5]) * wa1.y);
                s[6] = (short)f2b(b2f((ushort_t)u[6]) * wa1.z);
                s[7] = (short)f2b(b2f((ushort_t)u[7]) * wa1.w);
                *(bf16x8*)&vwa[((size_t)(b * 2 + p) * 128 + r0 + row) * 256 + d0] = s;
            } else {
                *(bf16x8*)&qbf[((size_t)(b * 2 + p) * 512 + r0 + row) * 256 + d0] = u;
            }
        }
        if (is_v) {
            // fused transpose: vT[bh][d][i], i = r0 + ic*8 + r, from O[i_loc][d]
#pragma unroll
            for (int it = 0; it < 4; ++it) {
                const int d  = (t & 63) + it * 64;
                const int ic = t >> 6;   // 0..3 -> 32 rows
                bf16x8 u;
#pragma unroll
                for (int r = 0; r < 8; ++r) u[r] = (short)O[ic * 8 + r][d];
                *(bf16x8*)&vT[((size_t)(b * 2 + p) * 256 + d) * 128 + r0 + ic * 8] = u;
            }
        }
        __syncthreads();
    }
}

// ---------------------------------------------------------------------------
// K2 att: per (b,h,j-tile 32): MFMA score -> column softmax -> att write ->
//     MFMA W = P^T V -> head partial via atomics.  (verified rounds 2/6;
//     round-7 512-block variant regressed +3.7us -> reverted byte-for-byte)
// ---------------------------------------------------------------------------
extern "C" __global__ void __launch_bounds__(256) att_kernel(
    char* __restrict__ ws, float* __restrict__ out)
{
    const ushort_t* qbf = (const ushort_t*)(ws + QBF_OFF);
    const ushort_t* vwa = (const ushort_t*)(ws + VWA_OFF);
    const ushort_t* vT  = (const ushort_t*)(ws + VT_OFF);
    float*          head = (float*)(ws + HEAD_OFF);
    float*          att_out = out + B_ * D_;

    __shared__ ushort_t q_lds[32][264];
    __shared__ ushort_t p_lds[32][136];
    __shared__ float wmax[4][32];
    __shared__ float wsum[4][32];

    const int t  = threadIdx.x;
    const int w  = t >> 6;
    const int l  = t & 63;
    const int l15 = l & 15, lg = l >> 4;

    const int bid = blockIdx.x;
    const int jt  = bid & 15;
    const int h   = (bid >> 4) & 1;
    const int b   = bid >> 5;
    const int j0  = jt * 32;
    const size_t bh = (size_t)(b * H_ + h);

    const ushort_t* vwa_p = vwa + bh * 128 * 256;
    const ushort_t* vT_p  = vT  + bh * 256 * 128;
    const ushort_t* qp    = qbf + (bh * 512 + j0) * 256;

    for (int c = t; c < 1024; c += 256) {
        const int row = c >> 5, c8 = (c & 31) * 8;
        *(bf16x8*)&q_lds[row][c8] = *(const bf16x8*)&qp[(size_t)row * 256 + c8];
    }
    __syncthreads();

    const ushort_t* a0 = vwa_p + (size_t)(w * 32 + l15) * 256 + lg * 8;
    const ushort_t* a1 = a0 + 16 * 256;
    const ushort_t* bq0 = &q_lds[l15][lg * 8];
    const ushort_t* bq1 = &q_lds[l15 + 16][lg * 8];

    f32x4 acc[2][2];
#pragma unroll
    for (int mb = 0; mb < 2; ++mb)
#pragma unroll
        for (int nb = 0; nb < 2; ++nb) acc[mb][nb] = (f32x4){0.f, 0.f, 0.f, 0.f};

#pragma unroll
    for (int ks = 0; ks < 8; ++ks) {
        const int ko = ks * 32;
        const bf16x8 A0 = *(const bf16x8*)(a0 + ko);
        const bf16x8 A1 = *(const bf16x8*)(a1 + ko);
        const bf16x8 B0 = *(const bf16x8*)(bq0 + ko);
        const bf16x8 B1 = *(const bf16x8*)(bq1 + ko);
        acc[0][0] = __builtin_amdgcn_mfma_f32_16x16x32_bf16(A0, B0, acc[0][0], 0, 0, 0);
        acc[0][1] = __builtin_amdgcn_mfma_f32_16x16x32_bf16(A0, B1, acc[0][1], 0, 0, 0);
        acc[1][0] = __builtin_amdgcn_mfma_f32_16x16x32_bf16(A1, B0, acc[1][0], 0, 0, 0);
        acc[1][1] = __builtin_amdgcn_mfma_f32_16x16x32_bf16(A1, B1, acc[1][1], 0, 0, 0);
    }

    float mx[2];
#pragma unroll
    for (int nb = 0; nb < 2; ++nb) {
        float m = acc[0][nb][0];
#pragma unroll
        for (int mb = 0; mb < 2; ++mb)
#pragma unroll
            for (int r = 0; r < 4; ++r) m = fmaxf(m, acc[mb][nb][r]);
        m = fmaxf(m, __shfl_xor(m, 16));
        m = fmaxf(m, __shfl_xor(m, 32));
        mx[nb] = m;
    }
    if (l < 16) { wmax[w][l] = mx[0]; wmax[w][l + 16] = mx[1]; }
    __syncthreads();

    float cm[2];
#pragma unroll
    for (int nb = 0; nb < 2; ++nb) {
        const int jl = nb * 16 + l15;
        cm[nb] = fmaxf(fmaxf(wmax[0][jl], wmax[1][jl]), fmaxf(wmax[2][jl], wmax[3][jl]));
    }

    float sm[2] = {0.f, 0.f};
#pragma unroll
    for (int mb = 0; mb < 2; ++mb)
#pragma unroll
        for (int nb = 0; nb < 2; ++nb)
#pragma unroll
            for (int r = 0; r < 4; ++r) {
                const float e = __expf(acc[mb][nb][r] - cm[nb]);
                acc[mb][nb][r] = e;
                sm[nb] += e;
            }
#pragma unroll
    for (int nb = 0; nb < 2; ++nb) {
        sm[nb] += __shfl_xor(sm[nb], 16);
        sm[nb] += __shfl_xor(sm[nb], 32);
    }
    if (l < 16) { wsum[w][l] = sm[0]; wsum[w][l + 16] = sm[1]; }
    __syncthreads();

    float cinv[2];
#pragma unroll
    for (int nb = 0; nb < 2; ++nb) {
        const int jl = nb * 16 + l15;
        cinv[nb] = 1.f / (wsum[0][jl] + wsum[1][jl] + wsum[2][jl] + wsum[3][jl]);
    }

    float* attp = att_out + (bh * 128) * 512 + j0;
#pragma unroll
    for (int mb = 0; mb < 2; ++mb) {
        const int il = w * 32 + mb * 16 + lg * 4;
#pragma unroll
        for (int nb = 0; nb < 2; ++nb) {
            const int jl = nb * 16 + l15;
            float p0 = acc[mb][nb][0] * cinv[nb];
            float p1 = acc[mb][nb][1] * cinv[nb];
            float p2 = acc[mb][nb][2] * cinv[nb];
            float p3 = acc[mb][nb][3] * cinv[nb];
            attp[(size_t)(il + 0) * 512 + jl] = p0;
            attp[(size_t)(il + 1) * 512 + jl] = p1;
            attp[(size_t)(il + 2) * 512 + jl] = p2;
            attp[(size_t)(il + 3) * 512 + jl] = p3;
            const uint_t u01 = (uint_t)f2b(p0) | ((uint_t)f2b(p1) << 16);
            const uint_t u23 = (uint_t)f2b(p2) | ((uint_t)f2b(p3) << 16);
            *(uint_t*)&p_lds[jl][il + 0] = u01;
            *(uint_t*)&p_lds[jl][il + 2] = u23;
        }
    }
    __syncthreads();

    f32x4 wacc[2][4];
#pragma unroll
    for (int mb = 0; mb < 2; ++mb)
#pragma unroll
        for (int nb = 0; nb < 4; ++nb) wacc[mb][nb] = (f32x4){0.f, 0.f, 0.f, 0.f};

    const ushort_t* pb0 = &p_lds[l15][lg * 8];
    const ushort_t* pb1 = &p_lds[l15 + 16][lg * 8];
    const ushort_t* vb0 = vT_p + (size_t)(w * 64 +  0 + l15) * 128 + lg * 8;
    const ushort_t* vb1 = vT_p + (size_t)(w * 64 + 16 + l15) * 128 + lg * 8;
    const ushort_t* vb2 = vT_p + (size_t)(w * 64 + 32 + l15) * 128 + lg * 8;
    const ushort_t* vb3 = vT_p + (size_t)(w * 64 + 48 + l15) * 128 + lg * 8;

#pragma unroll
    for (int ks = 0; ks < 4; ++ks) {
        const int ko = ks * 32;
        const bf16x8 PA0 = *(const bf16x8*)(pb0 + ko);
        const bf16x8 PA1 = *(const bf16x8*)(pb1 + ko);
        const bf16x8 VB0 = *(const bf16x8*)(vb0 + ko);
        const bf16x8 VB1 = *(const bf16x8*)(vb1 + ko);
        const bf16x8 VB2 = *(const bf16x8*)(vb2 + ko);
        const bf16x8 VB3 = *(const bf16x8*)(vb3 + ko);
        wacc[0][0] = __builtin_amdgcn_mfma_f32_16x16x32_bf16(PA0, VB0, wacc[0][0], 0, 0, 0);
        wacc[1][0] = __builtin_amdgcn_mfma_f32_16x16x32_bf16(PA1, VB0, wacc[1][0], 0, 0, 0);
        wacc[0][1] = __builtin_amdgcn_mfma_f32_16x16x32_bf16(PA0, VB1, wacc[0][1], 0, 0, 0);
        wacc[1][1] = __builtin_amdgcn_mfma_f32_16x16x32_bf16(PA1, VB1, wacc[1][1], 0, 0, 0);
        wacc[0][2] = __builtin_amdgcn_mfma_f32_16x16x32_bf16(PA0, VB2, wacc[0][2], 0, 0, 0);
        wacc[1][2] = __builtin_amdgcn_mfma_f32_16x16x32_bf16(PA1, VB2, wacc[1][2], 0, 0, 0);
        wacc[0][3] = __builtin_amdgcn_mfma_f32_16x16x32_bf16(PA0, VB3, wacc[0][3], 0, 0, 0);
        wacc[1][3] = __builtin_amdgcn_mfma_f32_16x16x32_bf16(PA1, VB3, wacc[1][3], 0, 0, 0);
    }

    float hd[4] = {0.f, 0.f, 0.f, 0.f};
#pragma unroll
    for (int nb = 0; nb < 4; ++nb) {
        const int d = w * 64 + nb * 16 + l15;
#pragma unroll
        for (int mb = 0; mb < 2; ++mb)
#pragma unroll
            for (int r = 0; r < 4; ++r) {
                const int jl = mb * 16 + lg * 4 + r;
                hd[nb] = fmaf(wacc[mb][nb][r], b2f(q_lds[jl][d]), hd[nb]);
            }
        hd[nb] += __shfl_xor(hd[nb], 16);
        hd[nb] += __shfl_xor(hd[nb], 32);
    }
    if (l < 16) {
        float* hp = head + bh * 256 + w * 64 + l;
        atomicAdd(hp +  0, hd[0]);
        atomicAdd(hp + 16, hd[1]);
        atomicAdd(hp + 32, hd[2]);
        atomicAdd(hp + 48, hd[3]);
    }
}

// ---------------------------------------------------------------------------
// K3 out: fused = head.reshape(8,512) @ Wo + bo.  32 blocks.
// ---------------------------------------------------------------------------
extern "C" __global__ void __launch_bounds__(256) out_kernel(
    const float* __restrict__ Wo, const float* __restrict__ bo,
    const char* __restrict__ ws, float* __restrict__ out)
{
    const float* head = (const float*)(ws + HEAD_OFF);
    __shared__ __align__(16) float hs[512];
    __shared__ float ored[4][64];

    const int bid = blockIdx.x, t = threadIdx.x;
    const int b = bid >> 2, cg = bid & 3;
    const int col = cg * 64 + (t & 63), kq = t >> 6;

    hs[t]       = head[(size_t)b * 512 + t];
    hs[t + 256] = head[(size_t)b * 512 + t + 256];
    __syncthreads();

    float acc = 0.f;
    const int kbeg = kq * 128;
    for (int k = kbeg; k < kbeg + 128; k += 4) {
        const float4 hk = *(const float4*)&hs[k];
        acc = fmaf(hk.x, Wo[(size_t)(k+0)*256 + col], acc);
        acc = fmaf(hk.y, Wo[(size_t)(k+1)*256 + col], acc);
        acc = fmaf(hk.z, Wo[(size_t)(k+2)*256 + col], acc);
        acc = fmaf(hk.w, Wo[(size_t)(k+3)*256 + col], acc);
    }
    ored[kq][t & 63] = acc;
    __syncthreads();
    if (t < 64) {
        const float r = ored[0][t] + ored[1][t] + ored[2][t] + ored[3][t] + bo[col];
        out[(size_t)b * 256 + col] = r;
    }
}

// ---------------------------------------------------------------------------
extern "C" void kernel_launch(void* const* d_in, const int* in_sizes, int n_in,
                              void* d_out, int out_size, void* d_ws, size_t ws_size,
                              hipStream_t stream)
{
    const float* v  = (const float*)d_in[0];
    const float* q  = (const float*)d_in[1];
    const float* Wv = (const float*)d_in[2];
    const float* bv = (const float*)d_in[3];
    const float* Wq = (const float*)d_in[4];
    const float* bq = (const float*)d_in[5];
    const float* wa = (const float*)d_in[6];
    // d_in[7] = ba: uniform shift within each softmax column -> no effect on outputs
    const float* Wo = (const float*)d_in[8];
    const float* bo = (const float*)d_in[9];
    float* out = (float*)d_out;
    char*  ws  = (char*)d_ws;

    hipLaunchKernelGGL(prep_kernel, dim3(32),  dim3(256), 0, stream, Wv, Wq, ws);
    hipLaunchKernelGGL(proj_kernel, dim3(160), dim3(256), 0, stream, v, q, bv, bq, wa, ws);
    hipLaunchKernelGGL(att_kernel,  dim3(256), dim3(256), 0, stream, ws, out);
    hipLaunchKernelGGL(out_kernel,  dim3(32),  dim3(256), 0, stream, Wo, bo, ws, out);
}